// Round 1
// 213.367 us; speedup vs baseline: 1.0487x; 1.0487x over previous
//
#include <hip/hip_runtime.h>
#include <hip/hip_bf16.h>

typedef __bf16 bf16x8 __attribute__((ext_vector_type(8)));
typedef float  f32x4  __attribute__((ext_vector_type(4)));
typedef short  s16x8  __attribute__((ext_vector_type(8)));
typedef unsigned short u16;

// round-to-nearest-even fp32 -> bf16 (as u16 bits)
static __device__ __forceinline__ u16 f2bf_rne(float f) {
  union { float f; unsigned u; } x; x.f = f;
  unsigned r = x.u + 0x7fffu + ((x.u >> 16) & 1u);
  return (u16)(r >> 16);
}

// split fp32 into bf16 hi (truncated) + bf16 lo (exact residual, truncated)
static __device__ __forceinline__ void splitbf(float f, short& hi, short& lo) {
  union { float f; unsigned u; } x; x.f = f;
  hi = (short)(x.u >> 16);
  union { unsigned u; float f; } h; h.u = x.u & 0xffff0000u;
  union { float f; unsigned u; } y; y.f = f - h.f;   // exact (Sterbenz)
  lo = (short)(y.u >> 16);
}

// async global->LDS, 16B per lane; LDS dest = uniform base + lane*16 (linear),
// so all layout swizzling is applied on the per-lane GLOBAL source address.
#define GLD_LDS16(g, l)                                                        \
  __builtin_amdgcn_global_load_lds(                                            \
      (const __attribute__((address_space(1))) void*)(g),                      \
      (__attribute__((address_space(3))) void*)(l), 16, 0, 0)

// One row per BLOCK, 4 waves cooperate. Wave w owns the 16-wide d-slice
// [16w, 16w+16). Stage Q,K,V rows (48KB) into LDS via 12 global_load_lds
// dwordx4 per wave (zero VGPR), then do the h-transpose via swizzled LDS
// reads. All LDS access patterns are <=2-way bank aliased (free).
//
// Swizzles (float-index within a 64-float h-row, matching staging source):
//   Q,K : e' = e ^ (((h>>3)&1)<<4)   (spreads the 4 quads' scalar reads)
//   V   : e' = e ^ ((h&15)<<2)       (spreads per-lane b128 reads)
//   P   : idx = d*64 + (e ^ ((d&15)<<2)), f32, overlays ldsK (dead after mm1)
__global__ __launch_bounds__(256, 3)
void attn64_kernel(const float* __restrict__ q, const float* __restrict__ k,
                   const float* __restrict__ v, float* __restrict__ out)
{
  __shared__ float ldsQ[4096];
  __shared__ float ldsK[4096];   // reused as swizzled f32 P after matmul1
  __shared__ float ldsV[4096];

  const int tid  = threadIdx.x;
  const int wid  = tid >> 6;
  const int lane = tid & 63;
  const int quad = lane >> 4;
  const int lo   = lane & 15;
  const int row  = blockIdx.x;

  const float* qrow = q + (size_t)row * 4096;
  const float* krow = k + (size_t)row * 4096;
  const float* vrow = v + (size_t)row * 4096;
  float*       orow = out + (size_t)row * 4096;

  // ---- Stage: 48 chunks of 1KB (4 h-rows each); wave w takes chunks
  // [4w,4w+4) of each buffer. Per-lane source addr carries the swizzle.
  {
    const int hl = lane >> 4;          // h-row within chunk
    const int e4 = (lane & 15) << 2;   // 4-float slot within row
#pragma unroll
    for (int i = 0; i < 4; ++i) {
      const int c = wid * 4 + i;
      const int h = c * 4 + hl;
      const int seQK = e4 ^ (((h >> 3) & 1) << 4);
      const int seV  = e4 ^ ((h & 15) << 2);
      GLD_LDS16(qrow + h * 64 + seQK, &ldsQ[c * 256]);
      GLD_LDS16(krow + h * 64 + seQK, &ldsK[c * 256]);
      GLD_LDS16(vrow + h * 64 + seV,  &ldsV[c * 256]);
    }
  }
  __syncthreads();   // drains vmcnt(0): all 48KB resident

  // ---- Q A-frags: A[m=d=wid*16+lo][k=h=ks*32+quad*8+j], hi/lo split.
  s16x8 qh[2], ql[2];
  {
    const int dcol = wid * 16 + lo;
#pragma unroll
    for (int ks = 0; ks < 2; ++ks)
#pragma unroll
      for (int j = 0; j < 8; ++j) {
        const int h = ks * 32 + quad * 8 + j;
        float x = ldsQ[h * 64 + (dcol ^ ((quad & 1) << 4))];
        short hh, ll; splitbf(x, hh, ll);
        qh[ks][j] = hh; ql[ks][j] = ll;
      }
  }

  // ---- Matmul 1: S[dslice][e] = sum_h Q[h][d] K[h][e].  24 MFMAs/wave.
  f32x4 acc[4];
#pragma unroll
  for (int et = 0; et < 4; ++et) acc[et] = (f32x4){0.f, 0.f, 0.f, 0.f};

#pragma unroll
  for (int et = 0; et < 4; ++et)
#pragma unroll
    for (int ks = 0; ks < 2; ++ks) {
      s16x8 kh, kl;
#pragma unroll
      for (int j = 0; j < 8; ++j) {
        const int h = ks * 32 + quad * 8 + j;
        float x = ldsK[h * 64 + ((lo + 16 * et) ^ ((quad & 1) << 4))];
        short hh, ll; splitbf(x, hh, ll);
        kh[j] = hh; kl[j] = ll;
      }
      bf16x8 ah = __builtin_bit_cast(bf16x8, qh[ks]);
      bf16x8 al = __builtin_bit_cast(bf16x8, ql[ks]);
      bf16x8 bh = __builtin_bit_cast(bf16x8, kh);
      bf16x8 bl = __builtin_bit_cast(bf16x8, kl);
      acc[et] = __builtin_amdgcn_mfma_f32_16x16x32_bf16(ah, bh, acc[et], 0, 0, 0);
      acc[et] = __builtin_amdgcn_mfma_f32_16x16x32_bf16(ah, bl, acc[et], 0, 0, 0);
      acc[et] = __builtin_amdgcn_mfma_f32_16x16x32_bf16(al, bh, acc[et], 0, 0, 0);
    }

  // ---- Softmax over e per row d. acc[et][r] = S[wid*16+quad*4+r][16et+lo];
  // each quad owns 4 rows, reduce across its 16 lanes.
#pragma unroll
  for (int r = 0; r < 4; ++r) {
    float m = fmaxf(fmaxf(acc[0][r], acc[1][r]), fmaxf(acc[2][r], acc[3][r]));
#pragma unroll
    for (int off = 1; off < 16; off <<= 1) m = fmaxf(m, __shfl_xor(m, off));
    float s = 0.f;
#pragma unroll
    for (int et = 0; et < 4; ++et) {
      float e0 = __expf(acc[et][r] - m);
      acc[et][r] = e0;
      s += e0;
    }
#pragma unroll
    for (int off = 1; off < 16; off <<= 1) s += __shfl_xor(s, off);
    float rs = 1.0f / s;
#pragma unroll
    for (int et = 0; et < 4; ++et) acc[et][r] *= rs;
  }

  __syncthreads();   // all waves done reading K -> safe to overlay P on ldsK

  // ---- P -> LDS (f32, swizzled). Each wave only re-reads its own d-slice,
  // so no further barrier is needed (within-wave DS ordering).
  float* P = ldsK;
#pragma unroll
  for (int r = 0; r < 4; ++r) {
    const int d   = wid * 16 + quad * 4 + r;
    const int swz = (d & 15) << 2;
#pragma unroll
    for (int et = 0; et < 4; ++et)
      P[d * 64 + ((lo + 16 * et) ^ swz)] = acc[et][r];
  }

  // ---- Matmul 2: Out[h][d] = sum_e V[h][e] P[d][e].  8 MFMAs/wave.
  f32x4 acc2[4];
#pragma unroll
  for (int mt = 0; mt < 4; ++mt) acc2[mt] = (f32x4){0.f, 0.f, 0.f, 0.f};

#pragma unroll
  for (int ks = 0; ks < 2; ++ks) {
    const int eb = quad * 8 + ks * 32;

    // B-frag from P: B[k=e=eb+j][n=d=wid*16+lo]
    const int dmine = wid * 16 + lo;
    const int pswz  = lo << 2;            // (dmine&15)<<2
    f32x4 p0 = *(const f32x4*)&P[dmine * 64 + (eb ^ pswz)];
    f32x4 p1 = *(const f32x4*)&P[dmine * 64 + ((eb + 4) ^ pswz)];
    s16x8 tp;
#pragma unroll
    for (int j = 0; j < 4; ++j) {
      tp[j]     = (short)f2bf_rne(p0[j]);
      tp[4 + j] = (short)f2bf_rne(p1[j]);
    }
    bf16x8 bp = __builtin_bit_cast(bf16x8, tp);

#pragma unroll
    for (int mt = 0; mt < 4; ++mt) {
      // A-frag from V: A[m=h=lo+16mt][k=e=eb+j]
      const int h    = lo + 16 * mt;
      const int vswz = lo << 2;           // (h&15)<<2
      f32x4 v0 = *(const f32x4*)&ldsV[h * 64 + (eb ^ vswz)];
      f32x4 v1 = *(const f32x4*)&ldsV[h * 64 + ((eb + 4) ^ vswz)];
      s16x8 tv;
#pragma unroll
      for (int j = 0; j < 4; ++j) {
        tv[j]     = (short)f2bf_rne(v0[j]);
        tv[4 + j] = (short)f2bf_rne(v1[j]);
      }
      bf16x8 av = __builtin_bit_cast(bf16x8, tv);
      acc2[mt] = __builtin_amdgcn_mfma_f32_16x16x32_bf16(av, bp, acc2[mt], 0, 0, 0);
    }
  }

  // ---- Store fp32: out[h*64+d], h = 16mt+quad*4+r, d = wid*16+lo.
#pragma unroll
  for (int mt = 0; mt < 4; ++mt)
#pragma unroll
    for (int r = 0; r < 4; ++r) {
      const int h = 16 * mt + quad * 4 + r;
      orow[h * 64 + wid * 16 + lo] = acc2[mt][r];
    }
}

extern "C" void kernel_launch(void* const* d_in, const int* in_sizes, int n_in,
                              void* d_out, int out_size, void* d_ws, size_t ws_size,
                              hipStream_t stream) {
  const float* q = (const float*)d_in[0];
  const float* k = (const float*)d_in[1];
  const float* v = (const float*)d_in[2];
  float* o = (float*)d_out;
  hipLaunchKernelGGL(attn64_kernel, dim3(4096), dim3(256), 0, stream, q, k, v, o);
}